// Round 1
// 374.818 us; speedup vs baseline: 1.1721x; 1.1721x over previous
//
#include <hip/hip_runtime.h>
#include <hip/hip_bf16.h>
#include <cmath>

// Problem constants
#define Bq   4
#define Lq   4096
#define Wq   2048
#define Hq   8
#define Mq   (Bq*Lq)        // 16384 rows
#define RCH  64             // rows per chunk
#define NCH  (Lq/RCH)       // 64 chunks per sequence

typedef __bf16 bf16;
typedef __attribute__((ext_vector_type(8))) __bf16 bf16x8;
typedef __attribute__((ext_vector_type(4))) float  f32x4;

// ---- workspace layout (bytes) ----
#define WS_WT    0                               // bf16 [2][8][256][256] = 2 MiB (n-major)
#define WS_C     (2*8*256*256*2)                 // float [2048]

// ---------------- K0: weight transpose/cast (LDS tiled) + c vector ----------------
__global__ __launch_bounds__(256) void prep2(const float* __restrict__ ig_w,
                                             const float* __restrict__ ag_w,
                                             const float* __restrict__ a_param,
                                             bf16* __restrict__ wt, float* __restrict__ c_arr) {
    __shared__ float t[64*65];
    int bid = blockIdx.x;                 // 256 blocks: [g:1][h:3][nt:2][kt:2]
    int kt = bid & 3, nt = (bid >> 2) & 3, h = (bid >> 4) & 7, g = bid >> 7;
    const float* src = g ? ag_w : ig_w;
    int rr = threadIdx.x >> 6, cc = threadIdx.x & 63;
#pragma unroll
    for (int p = 0; p < 16; p++) {
        int kl = p*4 + rr;
        t[kl*65 + cc] = src[h*65536 + (kt*64 + kl)*256 + nt*64 + cc];  // coalesced read
    }
    if (bid < 8) {
        float ap = a_param[bid*256 + threadIdx.x];
        c_arr[bid*256 + threadIdx.x] = 8.0f * log1pf(__expf(ap));      // 8*softplus
    }
    __syncthreads();
#pragma unroll
    for (int p = 0; p < 16; p++) {
        int nl = p*4 + rr;
        wt[((size_t)((g*8 + h)*256) + nt*64 + nl)*256 + kt*64 + cc] = (bf16)t[cc*65 + nl]; // coalesced write
    }
}

// ---------------- K1: fused persistent-chain RG-LRU ----------------
// 256 blocks = (stripe s:8)*(b:4)*(h:8), bid = s*32 + b*8 + h  -> siblings of an
// (b,h) x-slab share bid%8 == h -> same XCD under round-robin dispatch (L2 reuse).
// Each block owns 32 channels for one batch and walks all 64 chunks serially,
// carrying h in LDS. Weights stay in VGPRs for the whole kernel.
__global__ __launch_bounds__(256, 1) void rglru_fused(
    const float* __restrict__ x, const int* __restrict__ segpos,
    const float* __restrict__ prev_h,
    const bf16* __restrict__ wt, const float* __restrict__ igb,
    const float* __restrict__ agb, const float* __restrict__ c_arr,
    float* __restrict__ out)
{
    __shared__ float A_s[2][RCH*33];     // a            (stride 33: 2-way max on reads)
    __shared__ float G_s[2][RCH*33];     // gx*mult
    __shared__ float X_s[2][RCH*36];     // raw x cols   (stride 36: b128-write friendly)
    __shared__ float sgA[2][256], sgH[2][256];
    __shared__ float hc[2][32];          // carry, ping-pong

    const int tid = threadIdx.x;
    const int bid = blockIdx.x;
    const int h = bid & 7, b = (bid >> 3) & 3, s = bid >> 5;
    const int lane = tid & 63, wv = tid >> 6;
    const int l16 = lane & 15, quad = lane >> 4;
    const int wcol0 = h*256 + s*32;      // global channel base of this block

    // ---- weight fragments: B[k][n] for n = wcol0 + ct*16 + l16, all 8 k-slices.
    // 128 VGPR, loaded once, reused 64 chunks.
    bf16x8 wfx[2][8], wfa[2][8];
#pragma unroll
    for (int ct = 0; ct < 2; ct++) {
        const bf16* px = wt + ((size_t)(h*256 + s*32 + ct*16 + l16))*256 + quad*8;
        const bf16* pa = px + (size_t)Hq*256*256;
#pragma unroll
        for (int ks = 0; ks < 8; ks++) {
            wfx[ct][ks] = *(const bf16x8*)(px + (size_t)ks*32);
            wfa[ct][ks] = *(const bf16x8*)(pa + (size_t)ks*32);
        }
    }
    float bxv[2], bav[2], ccv[2];
#pragma unroll
    for (int ct = 0; ct < 2; ct++) {
        int wf = wcol0 + ct*16 + l16;
        bxv[ct] = igb[wf]; bav[ct] = agb[wf]; ccv[ct] = c_arr[wf];
    }
    if (tid < 32) hc[0][tid] = prev_h[b*Wq + wcol0 + tid];

    // per-lane x row pointer: lane (l16,quad) owns row wv*16+l16, k-cols quad*8..+7
    const float* xrow = x + ((size_t)b*Lq + wv*16 + l16)*Wq + h*256 + quad*8;

    // prefetch chunk 0 into registers (fragment-aligned: 2 float4 per k-slice)
    float4 xs[16];
#pragma unroll
    for (int ks = 0; ks < 8; ks++) {
        xs[2*ks]   = *(const float4*)(xrow + ks*32);
        xs[2*ks+1] = *(const float4*)(xrow + ks*32 + 4);
    }
    __syncthreads();

    int cur = 0;
    for (int c = 0; c < NCH; ++c) {
        // ---- GEMM: convert staged regs -> A-frags, MFMA against resident weights
        f32x4 ax[2] = {{0.f,0.f,0.f,0.f},{0.f,0.f,0.f,0.f}};
        f32x4 aa[2] = {{0.f,0.f,0.f,0.f},{0.f,0.f,0.f,0.f}};
#pragma unroll
        for (int ks = 0; ks < 8; ks++) {
            float4 u0 = xs[2*ks], u1 = xs[2*ks+1];
            if (ks == s) {   // this k-slice IS our output channel stripe: stash raw x
                float* xp = &X_s[cur][(wv*16 + l16)*36 + quad*8];
                *(float4*)xp = u0; *(float4*)(xp + 4) = u1;
            }
            bf16x8 af;
            af[0]=(bf16)u0.x; af[1]=(bf16)u0.y; af[2]=(bf16)u0.z; af[3]=(bf16)u0.w;
            af[4]=(bf16)u1.x; af[5]=(bf16)u1.y; af[6]=(bf16)u1.z; af[7]=(bf16)u1.w;
            ax[0] = __builtin_amdgcn_mfma_f32_16x16x32_bf16(af, wfx[0][ks], ax[0], 0,0,0);
            ax[1] = __builtin_amdgcn_mfma_f32_16x16x32_bf16(af, wfx[1][ks], ax[1], 0,0,0);
            aa[0] = __builtin_amdgcn_mfma_f32_16x16x32_bf16(af, wfa[0][ks], aa[0], 0,0,0);
            aa[1] = __builtin_amdgcn_mfma_f32_16x16x32_bf16(af, wfa[1][ks], aa[1], 0,0,0);
        }

        // ---- issue next chunk's x loads now; gates+scan (~600+ cyc) hide latency
        {
            const float* xn_ = xrow + (size_t)((c < NCH-1) ? c+1 : c)*RCH*Wq;
#pragma unroll
            for (int ks = 0; ks < 8; ks++) {
                xs[2*ks]   = *(const float4*)(xn_ + ks*32);
                xs[2*ks+1] = *(const float4*)(xn_ + ks*32 + 4);
            }
        }

        // ---- gates: lane holds cols ct*16+l16, rows wv*16+quad*4+r
#pragma unroll
        for (int r = 0; r < 4; r++) {
            int grow = wv*16 + quad*4 + r;
            bool rst = (segpos[c*RCH + grow] == 0);
#pragma unroll
            for (int ct = 0; ct < 2; ct++) {
                float zx = ax[ct][r] + bxv[ct];
                float za = aa[ct][r] + bav[ct];
                float gx = __builtin_amdgcn_rcpf(1.f + __expf(-zx));
                float ga = __builtin_amdgcn_rcpf(1.f + __expf(-za));
                float av = __expf(-ga * ccv[ct]);
                float mult = __builtin_amdgcn_sqrtf(fmaf(-av, av, 1.f)); // sqrt(1-a^2)
                if (rst) { av = 0.f; mult = 1.f; }
                A_s[cur][grow*33 + ct*16 + l16] = av;
                G_s[cur][grow*33 + ct*16 + l16] = gx * mult;
            }
        }
        __syncthreads();

        // ---- segmented scan: 32 cols x 8 segs of 8 rows, carry from hc
        const int col2 = tid & 31, seg = tid >> 5;
        float Pl[8], hl[8];
        float A = 1.f, hv = 0.f;
#pragma unroll
        for (int r = 0; r < 8; r++) {
            int grow = seg*8 + r;
            float a  = A_s[cur][grow*33 + col2];
            float xn = G_s[cur][grow*33 + col2] * X_s[cur][grow*36 + col2];
            hv = fmaf(a, hv, xn); A *= a;
            Pl[r] = A; hl[r] = hv;
        }
        sgA[cur][tid] = A; sgH[cur][tid] = hv;     // tid == seg*32+col2
        __syncthreads();
        float h0 = hc[c & 1][col2];
#pragma unroll
        for (int sp = 0; sp < 7; sp++)
            if (sp < seg) h0 = fmaf(sgA[cur][sp*32 + col2], h0, sgH[cur][sp*32 + col2]);

        float* yp = out + ((size_t)b*Lq + c*RCH + seg*8)*Wq + wcol0 + col2;
#pragma unroll
        for (int r = 0; r < 8; r++)
            yp[(size_t)r*Wq] = fmaf(Pl[r], h0, hl[r]);

        if (seg == 7) hc[(c+1) & 1][col2] = fmaf(Pl[7], h0, hl[7]);  // next carry (other buffer: no race)
        cur ^= 1;
    }
    __syncthreads();
    if (tid < 32) out[(size_t)Mq*Wq + b*Wq + wcol0 + tid] = hc[0][tid];  // last_h
}

extern "C" void kernel_launch(void* const* d_in, const int* in_sizes, int n_in,
                              void* d_out, int out_size, void* d_ws, size_t ws_size,
                              hipStream_t stream) {
    const float* x       = (const float*)d_in[0];
    const int*   segpos  = (const int*)  d_in[1];
    const float* prev_h  = (const float*)d_in[2];
    const float* ig_w    = (const float*)d_in[3];
    const float* ig_b    = (const float*)d_in[4];
    const float* ag_w    = (const float*)d_in[5];
    const float* ag_b    = (const float*)d_in[6];
    const float* a_param = (const float*)d_in[7];
    float* out = (float*)d_out;                    // [M*W] y then [B*W] last_h

    char* ws = (char*)d_ws;
    bf16*   wt    = (bf16*)  (ws + WS_WT);
    float*  c_arr = (float*) (ws + WS_C);

    prep2<<<256, 256, 0, stream>>>(ig_w, ag_w, a_param, wt, c_arr);
    rglru_fused<<<256, 256, 0, stream>>>(x, segpos, prev_h, wt, ig_b, ag_b, c_arr, out);
}